// Round 1
// 276.243 us; speedup vs baseline: 1.0411x; 1.0411x over previous
//
#include <hip/hip_runtime.h>

typedef unsigned short u16;
typedef unsigned int u32;

typedef __attribute__((ext_vector_type(8))) short bf16x8;
typedef __attribute__((ext_vector_type(4))) float f32x4;

static __device__ __forceinline__ u16 f2bf(float f) {
    u32 u = __float_as_uint(f);
    u32 r = (u + 0x7FFFu + ((u >> 16) & 1u)) >> 16;
    return (u16)r;
}
static __device__ __forceinline__ float bf2f(u16 h) {
    return __uint_as_float(((u32)h) << 16);
}
static __device__ __forceinline__ u32 pack2(float a, float b) {
    return (u32)f2bf(a) | ((u32)f2bf(b) << 16);
}

// ---------------- fp32 -> bf16 convert (vectorized) ----------------
__global__ __launch_bounds__(256) void convert_bf16_kernel(const float* __restrict__ x,
                                                           u16* __restrict__ y, int n4) {
    int i = blockIdx.x * 256 + threadIdx.x;
    if (i < n4) {
        float4 v = ((const float4*)x)[i];
        ushort4 o;
        o.x = f2bf(v.x); o.y = f2bf(v.y); o.z = f2bf(v.z); o.w = f2bf(v.w);
        ((ushort4*)y)[i] = o;
    }
}

// ---- 3x W [K,N] fp32 -> W^T [N,K] bf16, one dispatch (z selects matrix) ----
__global__ __launch_bounds__(256) void transpose3_to_bf16_kernel(
    const float* __restrict__ W0, const float* __restrict__ W1, const float* __restrict__ W2,
    u16* __restrict__ T0, u16* __restrict__ T1, u16* __restrict__ T2, int D) {
    __shared__ float t[32][33];
    const float* W = (blockIdx.z == 0) ? W0 : (blockIdx.z == 1) ? W1 : W2;
    u16* WT = (blockIdx.z == 0) ? T0 : (blockIdx.z == 1) ? T1 : T2;
    int bx = blockIdx.x, by = blockIdx.y;
    int tx = threadIdx.x, ty = threadIdx.y;
#pragma unroll
    for (int i = ty; i < 32; i += 8)
        t[i][tx] = W[(long)(by * 32 + i) * D + bx * 32 + tx];
    __syncthreads();
#pragma unroll
    for (int i = ty; i < 32; i += 8)
        WT[(long)(bx * 32 + i) * D + by * 32 + tx] = f2bf(t[tx][i]);
}

__global__ __launch_bounds__(256) void concat_bias_kernel(const float* __restrict__ a,
                                                          const float* __restrict__ b,
                                                          float* __restrict__ o, int n) {
    int i = blockIdx.x * 256 + threadIdx.x;
    if (i < 2 * n) o[i] = (i < n) ? a[i] : b[i - n];
}

// =====================================================================================
// 256x256-tile, BK=64, 8-wave (2Mx4N), 8-phase-style counted-vmcnt GEMM (T2+T3+T4+T5).
// C[m][n] = sum_k A[m][k]*B[n][k].  Per K-tile: 4 phases, each {ds_read subtile ||
// 2x global_load_lds -> s_barrier -> lgkmcnt(0) -> 16 MFMA -> s_barrier}; ONE
// s_waitcnt vmcnt(6) per K-tile (phase 4) -- loads stay in flight across barriers.
// Staging of tile u+2 goes into the buffer being computed, region-by-region, one
// phase AFTER that region's last ds_read (A-lo read P1/staged P2; B-hi of OTHER buf
// staged P1; B-lo read P1/staged P3; A-hi read P3/staged P4). Issue order per tile:
// A-lo(2) B-lo(2) A-hi(2) B-hi(2); vmcnt(6) at P4 => tile u+1 fully landed, newest 6
// (= u+2's A-lo,B-lo,A-hi) may remain in flight.
// LDS: 2 bufs x (A 256x64 + B 256x64) bf16 = 128 KiB. B rows stored class-remapped
// (j-lo stripes first) so each 8KB gload issue is one read-class. XOR swizzle
// slot ^= (ldsrow&7) on both gload source and ds_read => 8 bank-groups uniform.
// Requires K%64==0, K>=128, M%256==0, N%256==0, gridDim.x*gridDim.y%8==0.
// rs_mode: 0 plain; 1 softmax numerator (exp + atomic rowsum); 2 divide by rowsum.
// =====================================================================================
__global__ __launch_bounds__(512, 2) void gemm256_kernel(
    const u16* __restrict__ A, int lda, long sA,
    const u16* __restrict__ B, int ldb, long sB,
    void* __restrict__ C, int ldc, long sC, int c_bf16,
    const float* __restrict__ bias, int bias_mode,
    const float* __restrict__ madd, int mask_ld,
    float* __restrict__ rowsum, int rs_mode, int rs_ld,
    float scale, int K) {
    __shared__ __align__(16) u16 SMEM[2][2 * 256 * 64];  // per buf: A 16K elems | B 16K elems
    const int bz = blockIdx.z;
    const u16* Ab = A + (long)bz * sA;
    const u16* Bb = B + (long)bz * sB;
    // XCD-aware bijective swizzle over the (x,y) plane (nwg per z-plane % 8 == 0).
    int bx, by;
    {
        const int gx = gridDim.x;
        int flat = blockIdx.y * gx + blockIdx.x;
        const int cpx = (gx * gridDim.y) >> 3;
        flat = (flat & 7) * cpx + (flat >> 3);
        bx = flat % gx;
        by = flat / gx;
    }
    const int tm = by << 8, tn = bx << 8;
    const int tid = threadIdx.x, wave = tid >> 6, lane = tid & 63;
    const int wq = wave & 3;          // n-group 0..3
    const int wm = (wave >> 2) << 7;  // 0 or 128
    const int wn = wq << 6;           // 0,64,128,192
    const int fm = lane & 15, fq = lane >> 4;
    const int T = K >> 6;

    f32x4 acc[8][4];
#pragma unroll
    for (int i = 0; i < 8; i++)
#pragma unroll
        for (int j = 0; j < 4; j++) acc[i][j] = (f32x4){0.f, 0.f, 0.f, 0.f};

    const int srow = tid >> 3;   // 0..63: row within a 64-row gload issue
    const int sslot = tid & 7;   // 8B-pair slot 0..7

    auto stageA = [&](int t, int half) {  // half 0: LDS rows {0-63,128-191} (af-lo); 1: hi
        u16* dst = &SMEM[t & 1][0];
        const int kb = t << 6;
#pragma unroll
        for (int blk = 0; blk < 2; blk++) {
            const int r0 = blk * 128 + half * 64;
            const int r = r0 + srow;
            const int gk = kb + ((sslot ^ (r & 7)) << 3);
            const u16* ga = Ab + (long)(tm + r) * lda + gk;
            __builtin_amdgcn_global_load_lds(
                (const __attribute__((address_space(1))) void*)ga,
                (__attribute__((address_space(3))) void*)&dst[(r0 + wave * 8) * 64], 16, 0, 0);
        }
    };
    auto stageB = [&](int t, int half) {  // half 0: LDS rows 0-127 (j-lo class); 1: 128-255
        u16* dst = &SMEM[t & 1][256 * 64];
        const int kb = t << 6;
#pragma unroll
        for (int blk = 0; blk < 2; blk++) {
            const int r0 = half * 128 + blk * 64;
            const int r = r0 + srow;  // LDS row (class-major remap)
            const int g = ((r >> 5) & 3) * 64 + (r >> 7) * 32 + (r & 31);  // global row in tile
            const int gk = kb + ((sslot ^ (r & 7)) << 3);
            const u16* gb = Bb + (long)(tn + g) * ldb + gk;
            __builtin_amdgcn_global_load_lds(
                (const __attribute__((address_space(1))) void*)gb,
                (__attribute__((address_space(3))) void*)&dst[(r0 + wave * 8) * 64], 16, 0, 0);
        }
    };

    // Prologue: tile0 fully + tile1 A-lo,B-lo,A-hi (I1-I6). vmcnt(6) => tile0 landed.
    stageA(0, 0); stageB(0, 0); stageA(0, 1); stageB(0, 1);
    if (T > 1) {
        stageA(1, 0); stageB(1, 0); stageA(1, 1);
        asm volatile("s_waitcnt vmcnt(6)" ::: "memory");
    } else {
        asm volatile("s_waitcnt vmcnt(0)" ::: "memory");
    }
    __builtin_amdgcn_sched_barrier(0);
    __builtin_amdgcn_s_barrier();

    for (int u = 0; u < T; ++u) {
        const u16* As = &SMEM[u & 1][0];
        const u16* Bs = &SMEM[u & 1][256 * 64];
        bf16x8 alo[4][2], ahi[4][2], blo[2][2], bhi[2][2];
        // ---------- P1: read A-lo + B-lo; stage B-hi(u+1) into other buf ----------
#pragma unroll
        for (int i = 0; i < 4; i++) {
            const int ra = wm + i * 16 + fm;
            const int sw = ra & 7;
#pragma unroll
            for (int kh = 0; kh < 2; kh++)
                alo[i][kh] = *(const bf16x8*)&As[ra * 64 + (((kh * 4 + fq) ^ sw) << 3)];
        }
#pragma unroll
        for (int j = 0; j < 2; j++) {
            const int rb = wq * 32 + j * 16 + fm;
            const int sw = rb & 7;
#pragma unroll
            for (int kh = 0; kh < 2; kh++)
                blo[j][kh] = *(const bf16x8*)&Bs[rb * 64 + (((kh * 4 + fq) ^ sw) << 3)];
        }
        if (u + 1 < T) stageB(u + 1, 1);
        __builtin_amdgcn_sched_barrier(0);
        __builtin_amdgcn_s_barrier();
        asm volatile("s_waitcnt lgkmcnt(0)" ::: "memory");
        __builtin_amdgcn_sched_barrier(0);
        __builtin_amdgcn_s_setprio(1);
#pragma unroll
        for (int kh = 0; kh < 2; kh++)
#pragma unroll
            for (int i = 0; i < 4; i++)
#pragma unroll
                for (int j = 0; j < 2; j++)
                    acc[i][j] = __builtin_amdgcn_mfma_f32_16x16x32_bf16(alo[i][kh], blo[j][kh], acc[i][j], 0, 0, 0);
        __builtin_amdgcn_s_setprio(0);
        __builtin_amdgcn_sched_barrier(0);
        __builtin_amdgcn_s_barrier();
        // ---------- P2: read B-hi; stage A-lo(u+2); alo x bhi ----------
#pragma unroll
        for (int j = 0; j < 2; j++) {
            const int rb = 128 + wq * 32 + j * 16 + fm;
            const int sw = rb & 7;
#pragma unroll
            for (int kh = 0; kh < 2; kh++)
                bhi[j][kh] = *(const bf16x8*)&Bs[rb * 64 + (((kh * 4 + fq) ^ sw) << 3)];
        }
        if (u + 2 < T) stageA(u + 2, 0);
        __builtin_amdgcn_sched_barrier(0);
        __builtin_amdgcn_s_barrier();
        asm volatile("s_waitcnt lgkmcnt(0)" ::: "memory");
        __builtin_amdgcn_sched_barrier(0);
        __builtin_amdgcn_s_setprio(1);
#pragma unroll
        for (int kh = 0; kh < 2; kh++)
#pragma unroll
            for (int i = 0; i < 4; i++)
#pragma unroll
                for (int j = 0; j < 2; j++)
                    acc[i][2 + j] = __builtin_amdgcn_mfma_f32_16x16x32_bf16(alo[i][kh], bhi[j][kh], acc[i][2 + j], 0, 0, 0);
        __builtin_amdgcn_s_setprio(0);
        __builtin_amdgcn_sched_barrier(0);
        __builtin_amdgcn_s_barrier();
        // ---------- P3: read A-hi; stage B-lo(u+2); ahi x blo ----------
#pragma unroll
        for (int i = 0; i < 4; i++) {
            const int ra = wm + 64 + i * 16 + fm;
            const int sw = ra & 7;
#pragma unroll
            for (int kh = 0; kh < 2; kh++)
                ahi[i][kh] = *(const bf16x8*)&As[ra * 64 + (((kh * 4 + fq) ^ sw) << 3)];
        }
        if (u + 2 < T) stageB(u + 2, 0);
        __builtin_amdgcn_sched_barrier(0);
        __builtin_amdgcn_s_barrier();
        asm volatile("s_waitcnt lgkmcnt(0)" ::: "memory");
        __builtin_amdgcn_sched_barrier(0);
        __builtin_amdgcn_s_setprio(1);
#pragma unroll
        for (int kh = 0; kh < 2; kh++)
#pragma unroll
            for (int i = 0; i < 4; i++)
#pragma unroll
                for (int j = 0; j < 2; j++)
                    acc[4 + i][j] = __builtin_amdgcn_mfma_f32_16x16x32_bf16(ahi[i][kh], blo[j][kh], acc[4 + i][j], 0, 0, 0);
        __builtin_amdgcn_s_setprio(0);
        __builtin_amdgcn_sched_barrier(0);
        __builtin_amdgcn_s_barrier();
        // ---------- P4: stage A-hi(u+2); ahi x bhi; counted vmcnt ----------
        if (u + 2 < T) stageA(u + 2, 1);
        __builtin_amdgcn_s_setprio(1);
#pragma unroll
        for (int kh = 0; kh < 2; kh++)
#pragma unroll
            for (int i = 0; i < 4; i++)
#pragma unroll
                for (int j = 0; j < 2; j++)
                    acc[4 + i][2 + j] = __builtin_amdgcn_mfma_f32_16x16x32_bf16(ahi[i][kh], bhi[j][kh], acc[4 + i][2 + j], 0, 0, 0);
        __builtin_amdgcn_s_setprio(0);
        if (u + 2 < T) {
            asm volatile("s_waitcnt vmcnt(6)" ::: "memory");
        } else if (u + 1 < T) {
            asm volatile("s_waitcnt vmcnt(0)" ::: "memory");
        }
        __builtin_amdgcn_sched_barrier(0);
        __builtin_amdgcn_s_barrier();
    }
    __syncthreads();  // full drain before LDS reuse in epilogue

    // -------- epilogue: LDS transpose per 16-row i-block, fused bias/mask/exp/rowsum --------
    float* EP = (float*)&SMEM[0][0] + wave * 1088;
    const int row16 = lane >> 2, cb = (lane & 3) * 16;
    float4 bc[4];
    if (bias_mode == 1) {
#pragma unroll
        for (int q = 0; q < 4; q++) bc[q] = *(const float4*)&bias[tn + wn + cb + q * 4];
    }
#pragma unroll
    for (int i = 0; i < 8; i++) {
#pragma unroll
        for (int j = 0; j < 4; j++)
#pragma unroll
            for (int r = 0; r < 4; r++)
                EP[(fq * 4 + r) * 68 + j * 16 + fm] = acc[i][j][r];
        const long grow = tm + wm + i * 16 + row16;
        float rb = (bias_mode == 2) ? bias[grow] : 0.f;
        float4 t4[4];
#pragma unroll
        for (int q = 0; q < 4; q++) {
            float4 v = *(const float4*)&EP[row16 * 68 + cb + q * 4];
            v.x = v.x * scale + rb; v.y = v.y * scale + rb;
            v.z = v.z * scale + rb; v.w = v.w * scale + rb;
            if (bias_mode == 1) { v.x += bc[q].x; v.y += bc[q].y; v.z += bc[q].z; v.w += bc[q].w; }
            if (madd) {
                float4 m4 = *(const float4*)&madd[grow * mask_ld + tn + wn + cb + q * 4];
                v.x += m4.x; v.y += m4.y; v.z += m4.z; v.w += m4.w;
            }
            t4[q] = v;
        }
        if (rs_mode == 1) {
            float s = 0.f;
#pragma unroll
            for (int q = 0; q < 4; q++) {
                t4[q].x = __expf(t4[q].x); t4[q].y = __expf(t4[q].y);
                t4[q].z = __expf(t4[q].z); t4[q].w = __expf(t4[q].w);
                s += t4[q].x + t4[q].y + t4[q].z + t4[q].w;
            }
            s += __shfl_xor(s, 1);
            s += __shfl_xor(s, 2);
            if ((lane & 3) == 0) atomicAdd(&rowsum[(long)bz * rs_ld + grow], s);
        } else if (rs_mode == 2) {
            float inv = 1.f / rowsum[(long)bz * rs_ld + grow];
#pragma unroll
            for (int q = 0; q < 4; q++) {
                t4[q].x *= inv; t4[q].y *= inv; t4[q].z *= inv; t4[q].w *= inv;
            }
        }
        if (c_bf16) {
            u16* dst = (u16*)C + (long)bz * sC + grow * ldc + tn + wn + cb;
            uint4 o0 = {pack2(t4[0].x, t4[0].y), pack2(t4[0].z, t4[0].w),
                        pack2(t4[1].x, t4[1].y), pack2(t4[1].z, t4[1].w)};
            uint4 o1 = {pack2(t4[2].x, t4[2].y), pack2(t4[2].z, t4[2].w),
                        pack2(t4[3].x, t4[3].y), pack2(t4[3].z, t4[3].w)};
            *(uint4*)dst = o0;
            *(uint4*)(dst + 8) = o1;
        } else {
            float* dst = (float*)C + (long)bz * sC + grow * ldc + tn + wn + cb;
#pragma unroll
            for (int q = 0; q < 4; q++) *(float4*)(dst + q * 4) = t4[q];
        }
    }
}

// ================= 128x128-tile GEMM, BK=32, dbuf 32 KB (kept for VT + PV) =================
__global__ __launch_bounds__(256, 4) void gemm_bt_kernel(
    const u16* __restrict__ A, int lda, long sA,
    const u16* __restrict__ B, int ldb, long sB,
    void* __restrict__ C, int ldc, long sC, int c_bf16,
    const float* __restrict__ bias, int bias_mode,
    const float* __restrict__ madd, int mask_ld,
    float* __restrict__ rowsum, int rs_mode, int rs_ld, int swapxy,
    float scale, int K) {
    __shared__ __align__(16) u16 SMEM[2][256 * 32];  // As 128*32 + Bs 128*32 per buf
    const int bz = blockIdx.z;
    const u16* Ab = A + (long)bz * sA;
    const u16* Bb = B + (long)bz * sB;
    const int bxi = swapxy ? blockIdx.y : blockIdx.x;
    const int byi = swapxy ? blockIdx.x : blockIdx.y;
    const int tm = byi * 128, tn = bxi * 128;
    const int tid = threadIdx.x, wave = tid >> 6, lane = tid & 63;
    const int wm = (wave >> 1) * 64, wn = (wave & 1) * 64;
    const int lr = lane >> 2, c = lane & 3;
    const int fm = lane & 15, fq = lane >> 4;

    f32x4 acc[4][4];
#pragma unroll
    for (int i = 0; i < 4; i++)
#pragma unroll
        for (int j = 0; j < 4; j++) acc[i][j] = (f32x4){0.f, 0.f, 0.f, 0.f};

    const int T = K >> 5;

    auto stage = [&](int t, int buf) {
        u16* As = &SMEM[buf][0];
        u16* Bs = &SMEM[buf][128 * 32];
#pragma unroll
        for (int r = 0; r < 2; r++) {
            const int rl = r * 64 + wave * 16;
            const int row = rl + lr;
            const int kc = (t << 5) + ((c ^ ((row ^ (row >> 2)) & 3)) << 3);
            const u16* ga = Ab + (long)(tm + row) * lda + kc;
            const u16* gb = Bb + (long)(tn + row) * ldb + kc;
            __builtin_amdgcn_global_load_lds((const __attribute__((address_space(1))) void*)ga,
                                             (__attribute__((address_space(3))) void*)&As[rl * 32],
                                             16, 0, 0);
            __builtin_amdgcn_global_load_lds((const __attribute__((address_space(1))) void*)gb,
                                             (__attribute__((address_space(3))) void*)&Bs[rl * 32],
                                             16, 0, 0);
        }
    };

    stage(0, 0);
    __syncthreads();
    for (int t = 0; t < T; t++) {
        const int cur = t & 1;
        if (t + 1 < T) stage(t + 1, cur ^ 1);
        const u16* As = &SMEM[cur][0];
        const u16* Bs = &SMEM[cur][128 * 32];
        bf16x8 af[4], bfr[4];
#pragma unroll
        for (int i = 0; i < 4; i++) {
            int row = wm + i * 16 + fm;
            af[i] = *(const bf16x8*)&As[row * 32 + ((fq ^ ((row ^ (row >> 2)) & 3)) << 3)];
        }
#pragma unroll
        for (int j = 0; j < 4; j++) {
            int row = wn + j * 16 + fm;
            bfr[j] = *(const bf16x8*)&Bs[row * 32 + ((fq ^ ((row ^ (row >> 2)) & 3)) << 3)];
        }
#pragma unroll
        for (int i = 0; i < 4; i++)
#pragma unroll
            for (int j = 0; j < 4; j++)
                acc[i][j] = __builtin_amdgcn_mfma_f32_16x16x32_bf16(af[i], bfr[j], acc[i][j], 0, 0, 0);
        if (t + 1 < T) __syncthreads();
    }
    __syncthreads();

    float* EP = (float*)&SMEM[0][0] + wave * 1088;
    const int row16 = lane >> 2, cb = (lane & 3) * 16;
    float4 bc[4];
    if (bias_mode == 1) {
#pragma unroll
        for (int q = 0; q < 4; q++) bc[q] = *(const float4*)&bias[tn + wn + cb + q * 4];
    }
#pragma unroll
    for (int i = 0; i < 4; i++) {
#pragma unroll
        for (int j = 0; j < 4; j++)
#pragma unroll
            for (int r = 0; r < 4; r++)
                EP[(fq * 4 + r) * 68 + j * 16 + fm] = acc[i][j][r];
        const long grow = tm + wm + i * 16 + row16;
        float rb = (bias_mode == 2) ? bias[grow] : 0.f;
        float4 t4[4];
#pragma unroll
        for (int q = 0; q < 4; q++) {
            float4 v = *(const float4*)&EP[row16 * 68 + cb + q * 4];
            v.x = v.x * scale + rb; v.y = v.y * scale + rb;
            v.z = v.z * scale + rb; v.w = v.w * scale + rb;
            if (bias_mode == 1) { v.x += bc[q].x; v.y += bc[q].y; v.z += bc[q].z; v.w += bc[q].w; }
            if (madd) {
                float4 m4 = *(const float4*)&madd[grow * mask_ld + tn + wn + cb + q * 4];
                v.x += m4.x; v.y += m4.y; v.z += m4.z; v.w += m4.w;
            }
            t4[q] = v;
        }
        if (rs_mode == 1) {
            float s = 0.f;
#pragma unroll
            for (int q = 0; q < 4; q++) {
                t4[q].x = __expf(t4[q].x); t4[q].y = __expf(t4[q].y);
                t4[q].z = __expf(t4[q].z); t4[q].w = __expf(t4[q].w);
                s += t4[q].x + t4[q].y + t4[q].z + t4[q].w;
            }
            s += __shfl_xor(s, 1);
            s += __shfl_xor(s, 2);
            if ((lane & 3) == 0) atomicAdd(&rowsum[(long)bz * rs_ld + grow], s);
        } else if (rs_mode == 2) {
            float inv = 1.f / rowsum[(long)bz * rs_ld + grow];
#pragma unroll
            for (int q = 0; q < 4; q++) {
                t4[q].x *= inv; t4[q].y *= inv; t4[q].z *= inv; t4[q].w *= inv;
            }
        }
        if (c_bf16) {
            u16* dst = (u16*)C + (long)bz * sC + grow * ldc + tn + wn + cb;
            uint4 o0 = {pack2(t4[0].x, t4[0].y), pack2(t4[0].z, t4[0].w),
                        pack2(t4[1].x, t4[1].y), pack2(t4[1].z, t4[1].w)};
            uint4 o1 = {pack2(t4[2].x, t4[2].y), pack2(t4[2].z, t4[2].w),
                        pack2(t4[3].x, t4[3].y), pack2(t4[3].z, t4[3].w)};
            *(uint4*)dst = o0;
            *(uint4*)(dst + 8) = o1;
        } else {
            float* dst = (float*)C + (long)bz * sC + grow * ldc + tn + wn + cb;
#pragma unroll
            for (int q = 0; q < 4; q++) *(float4*)(dst + q * 4) = t4[q];
        }
    }
}

extern "C" void kernel_launch(void* const* d_in, const int* in_sizes, int n_in,
                              void* d_out, int out_size, void* d_ws, size_t ws_size,
                              hipStream_t stream) {
    const float* x    = (const float*)d_in[0];
    const float* mask = (const float*)d_in[1];
    const float* Wq   = (const float*)d_in[2];
    const float* bq   = (const float*)d_in[3];
    const float* Wk   = (const float*)d_in[4];
    const float* bk   = (const float*)d_in[5];
    const float* Wv   = (const float*)d_in[6];
    const float* bv   = (const float*)d_in[7];
    float* out = (float*)d_out;

    const int B = 4, S = 2048, D = 1024;
    const long MS = (long)B * S;  // 8192

    size_t need = (size_t)MS * D * 2 + (size_t)(2 * D) * D * 2 + (size_t)D * D * 2
                + (size_t)(2 * D) * 4 + (size_t)MS * (2 * D) * 2 + (size_t)D * MS * 2
                + (size_t)B * S * S * 2 + (size_t)B * S * 4;
    if (ws_size < need) return;

    char* ws = (char*)d_ws;
    u16*  xb   = (u16*)ws;  ws += (long)MS * D * 2;
    u16*  wqkt = (u16*)ws;  ws += (long)(2 * D) * D * 2;
    u16*  wvt  = (u16*)ws;  ws += (long)D * D * 2;
    float* bqk = (float*)ws; ws += (long)(2 * D) * 4;
    u16*  QK   = (u16*)ws;  ws += (long)MS * (2 * D) * 2;
    u16*  VT   = (u16*)ws;  ws += (long)D * MS * 2;
    u16*  sc   = (u16*)ws;  ws += (long)B * S * S * 2;
    float* rsum = (float*)ws; ws += (long)B * S * 4;

    const float SCALE = 0.03125f;  // 1/sqrt(1024)

    hipMemsetAsync(rsum, 0, (size_t)B * S * 4, stream);

    convert_bf16_kernel<<<(int)((MS * D / 4 + 255) / 256), 256, 0, stream>>>(x, xb, (int)(MS * D / 4));
    transpose3_to_bf16_kernel<<<dim3(32, 32, 3), dim3(32, 8), 0, stream>>>(
        Wq, Wk, Wv, wqkt, wqkt + (long)D * D, wvt, D);
    concat_bias_kernel<<<8, 256, 0, stream>>>(bq, bk, bqk, D);

    // QK projection: [8192, 2048] bf16, 256x256 8-phase tiles -> grid (8, 32), 1 block/CU
    gemm256_kernel<<<dim3(2 * D / 256, (int)(MS / 256), 1), 512, 0, stream>>>(
        xb, D, 0, wqkt, D, 0, QK, 2 * D, 0, 1, bqk, 1, nullptr, 0,
        nullptr, 0, 0, 1.0f, D);
    // V^T [1024, 8192] bf16: 128^2 tiles, grid (64, 8)
    gemm_bt_kernel<<<dim3((int)(MS / 128), D / 128, 1), 256, 0, stream>>>(
        wvt, D, 0, xb, D, 0, VT, (int)MS, 0, 1, bv, 2, nullptr, 0,
        nullptr, 0, 0, 0, 1.0f, D);

    // scores: exp((Q.K^T)*scale + mask) -> bf16, rowsum accumulated (softmax numerator)
    // 256x256 8-phase tiles -> grid (8, 8, 4) = 256 blocks
    gemm256_kernel<<<dim3(S / 256, S / 256, B), 512, 0, stream>>>(
        QK, 2 * D, (long)S * 2 * D, QK + D, 2 * D, (long)S * 2 * D, sc, S, (long)S * S, 1,
        nullptr, 0, mask, S, rsum, 1, S, SCALE, D);

    // PV: out = (exp-scores @ VT^T) / rowsum  (softmax denominator fused in epilogue).
    // swapxy=1 + grid (q-tiles, d-tiles): XCD = q%8 -> sc footprint 4 MB/XCD (L2-resident).
    gemm_bt_kernel<<<dim3(S / 128, D / 128, B), 256, 0, stream>>>(
        sc, S, (long)S * S, VT, (int)MS, (long)S, out, D, (long)S * D, 0,
        nullptr, 0, nullptr, 0, rsum, 2, S, 1, 1.0f, S);
}